// Round 18
// baseline (88.742 us; speedup 1.0000x reference)
//
#include <hip/hip_runtime.h>
#include <hip/hip_bf16.h>

typedef unsigned short u16;
typedef unsigned int u32;
typedef __bf16 bf16x8_t __attribute__((ext_vector_type(8)));
typedef float f32x4_t __attribute__((ext_vector_type(4)));

constexpr int Bb = 4;
constexpr int Tt = 4096;
constexpr int Dd = 64;
constexpr float QSCALE = 0.18033688011112042f; // 0.125 * log2(e), folded into q

__device__ __forceinline__ u16 f2bf(float f) { // RNE
  unsigned int u = __builtin_bit_cast(unsigned int, f);
  return (u16)((u + 0x7fffu + ((u >> 16) & 1u)) >> 16);
}
__device__ __forceinline__ u32 pk2(float a, float b) { // RNE pack
  return (u32)f2bf(a) | ((u32)f2bf(b) << 16);
}
__device__ __forceinline__ u32 pkt(float a, float b) { // truncation pack (3 inst)
  const u32 ua = __builtin_bit_cast(u32, a);
  const u32 ub = __builtin_bit_cast(u32, b);
  return (ua >> 16) | (ub & 0xFFFF0000u);
}
__device__ __forceinline__ bf16x8_t ld16(const u16* p) {
  int4 v = *(const int4*)p;
  return __builtin_bit_cast(bf16x8_t, v);
}
__device__ __forceinline__ f32x4_t mfma16(bf16x8_t a, bf16x8_t b, f32x4_t c) {
  return __builtin_amdgcn_mfma_f32_16x16x32_bf16(a, b, c, 0, 0, 0);
}

// ---------------- proj v4 (R17, verified): LDS-staged x and W, fragment-order outputs ----------------
//   qS/kS tile (b*64+t): frag(idx,kk) @ (idx*2+kk)*512 + lane*8 u16
//   vS  tile (b*64+kt):  frag(kk,dt)  @ (kk*4+dt)*512 + lane*8 u16
__global__ __launch_bounds__(256) void HeadV1_proj(
    const float* __restrict__ x, const float* __restrict__ Wk,
    const float* __restrict__ Wq, const float* __restrict__ Wv,
    u16* __restrict__ qS, u16* __restrict__ kS, u16* __restrict__ vS)
{
  __shared__ u16 xl[64][72];      // 9216 B
  __shared__ u16 Wl[3][64][72];   // 27648 B
  __shared__ u16 ylds[64][72];    // 9216 B  (total 46 KB)

  const int t = threadIdx.x;
  const int w = t >> 6, lane = t & 63, l15 = lane & 15, quad = lane >> 4;
  const int r0 = blockIdx.x * 64;
  const int b  = r0 >> 12;
  const int kt = (r0 & 4095) >> 6;
  const long tilebase = ((long)(b * 64 + kt)) * 4096;

  { // coalesced fp32 staging with one-time bf16 conversion
    const float* srcs[4] = {x + (long)r0 * 64, Wk, Wq, Wv};
    u16* dstl[4] = {&xl[0][0], &Wl[0][0][0], &Wl[1][0][0], &Wl[2][0][0]};
    #pragma unroll
    for (int mm = 0; mm < 4; mm++) {
      const float* s = srcs[mm];
      u16* d = dstl[mm];
      #pragma unroll
      for (int i = 0; i < 4; i++) {
        const int f4 = i * 256 + t;        // 1024 float4 per 64x64 tile
        const int row = f4 >> 4, c4 = f4 & 15;
        float4 v = ((const float4*)(s + row * 64))[c4];
        uint2 pk;
        pk.x = pk2(v.x, v.y);
        pk.y = pk2(v.z, v.w);
        *(uint2*)(d + row * 72 + c4 * 4) = pk;
      }
    }
  }
  __syncthreads();

  bf16x8_t xf[2];
  #pragma unroll
  for (int kh = 0; kh < 2; kh++)
    xf[kh] = ld16(&xl[w * 16 + l15][kh * 32 + quad * 8]);

  u16* dsts[3];
  dsts[0] = kS + tilebase; dsts[1] = qS + tilebase; dsts[2] = vS + tilebase;

  #pragma unroll
  for (int m = 0; m < 3; m++) {
    float vals[4][4];
    #pragma unroll
    for (int g = 0; g < 4; g++) {
      f32x4_t acc = {0.f, 0.f, 0.f, 0.f};
      #pragma unroll
      for (int kh = 0; kh < 2; kh++) {
        bf16x8_t wf = ld16(&Wl[m][g * 16 + l15][kh * 32 + quad * 8]);
        acc = mfma16(xf[kh], wf, acc);
      }
      #pragma unroll
      for (int r = 0; r < 4; r++)
        vals[g][r] = (m == 1) ? acc[r] * QSCALE : acc[r];
    }
    #pragma unroll
    for (int g = 0; g < 4; g++)
      #pragma unroll
      for (int r = 0; r < 4; r++)
        ylds[w * 16 + quad * 4 + r][g * 16 + l15] = f2bf(vals[g][r]);
    __syncthreads();
    if (m < 2) {
      #pragma unroll
      for (int kk = 0; kk < 2; kk++) {
        bf16x8_t f = ld16(&ylds[w * 16 + l15][kk * 32 + quad * 8]);
        *(int4*)(dsts[m] + (w * 2 + kk) * 512 + lane * 8) = __builtin_bit_cast(int4, f);
      }
    } else {
      #pragma unroll
      for (int kk = 0; kk < 2; kk++) {
        u16 tmp[8];
        #pragma unroll
        for (int j = 0; j < 8; j++)
          tmp[j] = ylds[kk * 32 + quad * 8 + j][w * 16 + l15];
        *(int4*)(dsts[2] + (kk * 4 + w) * 512 + lane * 8) = *(const int4*)tmp;
      }
    }
    __syncthreads();
  }
}

// ---------------- flash v9: ONE LDS chain per kv-tile (full P-tile before PV) ----------------
// 512 blocks x 512 thr, 2 blocks/CU. b = blk&3, u = blk>>2, j = u<64 ? u : 191-u.
// Per tile: all 4rt x 2ct QK+exp2+pack (independent, back-to-back) -> single lgkmcnt
// barrier -> full PV (20 MFMA). pT stride 76 u16: b128 read bank-bases all distinct.
// LDS: pT [8][32][76]u16 @0 (38912); lst [8][32]f32 @38912 (1024) -> 39936 total.
// Merge overlays pT: chk [8][16][33]f32 @0 (16896), stg [32][68]f32 @16896 (8704).
__global__ __launch_bounds__(512, 4) void HeadV1_flash(
    const u16* __restrict__ qS, const u16* __restrict__ kS,
    const u16* __restrict__ vS, float* __restrict__ outg)
{
  __shared__ __align__(16) char smem[39936];
  u16  (*pT)[32][76]   = (u16 (*)[32][76])smem;
  float (*chk)[16][33] = (float (*)[16][33])smem;
  float (*stg)[68]     = (float (*)[68])(smem + 16896);
  float (*lst)[32]     = (float (*)[32])(smem + 38912);

  const int t    = threadIdx.x;
  const int w    = t >> 6;        // 0..7
  const int lane = t & 63;
  const int l15  = lane & 15;
  const int quad = lane >> 4;

  const int b = blockIdx.x & 3;
  const int u = blockIdx.x >> 2;            // 0..127
  const int j = (u < 64) ? u : (191 - u);   // q-tile-32 index, pair-balanced
  const int qt64 = j >> 1;
  const int ql0  = (j & 1) * 32;
  const int qr0  = j * 32;
  const long base = (long)b * Tt * Dd;

  union { u32 u4[4]; bf16x8_t v; } uo;
  uo.u4[0] = uo.u4[1] = uo.u4[2] = uo.u4[3] = 0x3F803F80u; // bf16 1.0 x8
  const bf16x8_t ones = uo.v;
  const f32x4_t zero4 = {0.f, 0.f, 0.f, 0.f};

  const u16* qtile = qS + ((long)(b * 64 + qt64)) * 4096 + lane * 8;
  bf16x8_t qfrag[2][2];
  #pragma unroll
  for (int ct = 0; ct < 2; ct++)
    #pragma unroll
    for (int kd = 0; kd < 2; kd++)
      qfrag[ct][kd] = ld16(qtile + ((ql0 / 16 + ct) * 2 + kd) * 512);

  f32x4_t O[4][2];   // [dt][ct]
  #pragma unroll
  for (int a = 0; a < 4; a++)
    #pragma unroll
    for (int c = 0; c < 2; c++)
      O[a][c] = zero4;
  f32x4_t Lc[2] = {zero4, zero4};

  const int nk = (j >> 1) + 1;   // kv tiles of 64

  for (int kt = w; kt < nk; kt += 8) {
    const bool ismask = (kt == nk - 1);
    const int kv0 = kt * 64;
    const u16* ktile = kS + ((long)(b * 64 + kt)) * 4096 + lane * 8;
    const u16* vtile = vS + ((long)(b * 64 + kt)) * 4096 + lane * 8;

    // ---- phase 1: ENTIRE P-tile (all independent, no intermediate waits) ----
    #pragma unroll
    for (int rt = 0; rt < 4; rt++) {
      bf16x8_t kf0 = ld16(ktile + (rt * 2 + 0) * 512);
      bf16x8_t kf1 = ld16(ktile + (rt * 2 + 1) * 512);
      #pragma unroll
      for (int ct = 0; ct < 2; ct++) {
        f32x4_t acc = zero4;
        acc = mfma16(kf0, qfrag[ct][0], acc);
        acc = mfma16(kf1, qfrag[ct][1], acc);
        if (ismask) {
          const int kvl = kv0 + rt * 16 + quad * 4;
          const int qi  = qr0 + ct * 16 + l15;
          #pragma unroll
          for (int r = 0; r < 4; r++)
            if (kvl + r > qi) acc[r] = -1e30f;   // v_exp -> 0
        }
        const float p0 = __builtin_amdgcn_exp2f(acc[0]);
        const float p1 = __builtin_amdgcn_exp2f(acc[1]);
        const float p2 = __builtin_amdgcn_exp2f(acc[2]);
        const float p3 = __builtin_amdgcn_exp2f(acc[3]);
        uint2 pk;
        pk.x = pkt(p0, p1);
        pk.y = pkt(p2, p3);
        *(uint2*)&pT[w][ct * 16 + l15][rt * 16 + quad * 4] = pk;
      }
    }

    // ---- phase 2: full PV after ONE LDS wait (per-wave pT region, no barrier) ----
    #pragma unroll
    for (int kk = 0; kk < 2; kk++) {
      bf16x8_t vf[4];
      #pragma unroll
      for (int dt = 0; dt < 4; dt++)
        vf[dt] = ld16(vtile + (kk * 4 + dt) * 512);
      #pragma unroll
      for (int ct = 0; ct < 2; ct++) {
        bf16x8_t pf = ld16(&pT[w][ct * 16 + l15][kk * 32 + quad * 8]);
        #pragma unroll
        for (int dt = 0; dt < 4; dt++)
          O[dt][ct] = mfma16(vf[dt], pf, O[dt][ct]);
        Lc[ct] = mfma16(ones, pf, Lc[ct]);
      }
    }
  }

  // ---- 8-wave merge ----
  if (quad == 0) {
    #pragma unroll
    for (int ct = 0; ct < 2; ct++)
      lst[w][ct * 16 + l15] = Lc[ct][0];
  }
  __syncthreads();  // pT dead past here; chk/stg overlay it

  #pragma unroll
  for (int dt = 0; dt < 4; dt++) {
    #pragma unroll
    for (int ct = 0; ct < 2; ct++)
      #pragma unroll
      for (int r = 0; r < 4; r++)
        chk[w][quad * 4 + r][ct * 16 + l15] = O[dt][ct][r];
    __syncthreads();
    {
      const int d2 = t >> 5, q = t & 31;   // 512 threads = 16 d x 32 q
      float s = 0.f;
      #pragma unroll
      for (int w2 = 0; w2 < 8; w2++) s += chk[w2][d2][q];
      stg[q][dt * 16 + d2] = s;
    }
    __syncthreads();
  }

  { // normalize + coalesced fp32 write: 32 q x 64 d (512 thr x 16 B)
    const int q = t >> 4, dg = t & 15;
    float L = 0.f;
    #pragma unroll
    for (int w2 = 0; w2 < 8; w2++) L += lst[w2][q];
    const float invL = 1.0f / L;
    float4 v = *(const float4*)&stg[q][dg * 4];
    v.x *= invL; v.y *= invL; v.z *= invL; v.w *= invL;
    *(float4*)(outg + base + (long)(qr0 + q) * 64 + dg * 4) = v;
  }
}

extern "C" void kernel_launch(void* const* d_in, const int* in_sizes, int n_in,
                              void* d_out, int out_size, void* d_ws, size_t ws_size,
                              hipStream_t stream) {
  (void)in_sizes; (void)n_in; (void)out_size; (void)ws_size;
  const float* x  = (const float*)d_in[0];
  const float* Wk = (const float*)d_in[1];
  const float* Wq = (const float*)d_in[2];
  const float* Wv = (const float*)d_in[3];
  float* out = (float*)d_out;
  // workspace: qS 2MB | kS 2MB | vS 2MB (all in MFMA-fragment order)
  u16* qw  = (u16*)d_ws;
  u16* kw  = qw + (size_t)Bb * Tt * Dd;
  u16* vw  = kw + (size_t)Bb * Tt * Dd;

  HeadV1_proj<<<(Bb * Tt) / 64, 256, 0, stream>>>(x, Wk, Wq, Wv, qw, kw, vw);
  HeadV1_flash<<<512, 512, 0, stream>>>(qw, kw, vw, out);
}

// Round 19
// 85.488 us; speedup vs baseline: 1.0381x; 1.0381x over previous
//
#include <hip/hip_runtime.h>
#include <hip/hip_bf16.h>

typedef unsigned short u16;
typedef unsigned int u32;
typedef __bf16 bf16x8_t __attribute__((ext_vector_type(8)));
typedef float f32x4_t __attribute__((ext_vector_type(4)));

constexpr int Bb = 4;
constexpr int Tt = 4096;
constexpr int Dd = 64;
constexpr float QSCALE = 0.18033688011112042f; // 0.125 * log2(e), folded into q

__device__ __forceinline__ u16 f2bf(float f) { // RNE
  unsigned int u = __builtin_bit_cast(unsigned int, f);
  return (u16)((u + 0x7fffu + ((u >> 16) & 1u)) >> 16);
}
__device__ __forceinline__ u32 pk2(float a, float b) { // RNE pack
  return (u32)f2bf(a) | ((u32)f2bf(b) << 16);
}
__device__ __forceinline__ u32 pkt(float a, float b) { // truncation pack (3 inst)
  const u32 ua = __builtin_bit_cast(u32, a);
  const u32 ub = __builtin_bit_cast(u32, b);
  return (ua >> 16) | (ub & 0xFFFF0000u);
}
__device__ __forceinline__ bf16x8_t ld16(const u16* p) {
  int4 v = *(const int4*)p;
  return __builtin_bit_cast(bf16x8_t, v);
}
__device__ __forceinline__ f32x4_t mfma16(bf16x8_t a, bf16x8_t b, f32x4_t c) {
  return __builtin_amdgcn_mfma_f32_16x16x32_bf16(a, b, c, 0, 0, 0);
}

// ---------------- proj v4 (R17, verified): LDS-staged x and W, fragment-order outputs ----------------
//   qS/kS tile (b*64+t): frag(idx,kk) @ (idx*2+kk)*512 + lane*8 u16
//   vS  tile (b*64+kt):  frag(kk,dt)  @ (kk*4+dt)*512 + lane*8 u16
__global__ __launch_bounds__(256) void HeadV1_proj(
    const float* __restrict__ x, const float* __restrict__ Wk,
    const float* __restrict__ Wq, const float* __restrict__ Wv,
    u16* __restrict__ qS, u16* __restrict__ kS, u16* __restrict__ vS)
{
  __shared__ u16 xl[64][72];      // 9216 B
  __shared__ u16 Wl[3][64][72];   // 27648 B
  __shared__ u16 ylds[64][72];    // 9216 B  (total 46 KB)

  const int t = threadIdx.x;
  const int w = t >> 6, lane = t & 63, l15 = lane & 15, quad = lane >> 4;
  const int r0 = blockIdx.x * 64;
  const int b  = r0 >> 12;
  const int kt = (r0 & 4095) >> 6;
  const long tilebase = ((long)(b * 64 + kt)) * 4096;

  { // coalesced fp32 staging with one-time bf16 conversion
    const float* srcs[4] = {x + (long)r0 * 64, Wk, Wq, Wv};
    u16* dstl[4] = {&xl[0][0], &Wl[0][0][0], &Wl[1][0][0], &Wl[2][0][0]};
    #pragma unroll
    for (int mm = 0; mm < 4; mm++) {
      const float* s = srcs[mm];
      u16* d = dstl[mm];
      #pragma unroll
      for (int i = 0; i < 4; i++) {
        const int f4 = i * 256 + t;        // 1024 float4 per 64x64 tile
        const int row = f4 >> 4, c4 = f4 & 15;
        float4 v = ((const float4*)(s + row * 64))[c4];
        uint2 pk;
        pk.x = pk2(v.x, v.y);
        pk.y = pk2(v.z, v.w);
        *(uint2*)(d + row * 72 + c4 * 4) = pk;
      }
    }
  }
  __syncthreads();

  bf16x8_t xf[2];
  #pragma unroll
  for (int kh = 0; kh < 2; kh++)
    xf[kh] = ld16(&xl[w * 16 + l15][kh * 32 + quad * 8]);

  u16* dsts[3];
  dsts[0] = kS + tilebase; dsts[1] = qS + tilebase; dsts[2] = vS + tilebase;

  #pragma unroll
  for (int m = 0; m < 3; m++) {
    float vals[4][4];
    #pragma unroll
    for (int g = 0; g < 4; g++) {
      f32x4_t acc = {0.f, 0.f, 0.f, 0.f};
      #pragma unroll
      for (int kh = 0; kh < 2; kh++) {
        bf16x8_t wf = ld16(&Wl[m][g * 16 + l15][kh * 32 + quad * 8]);
        acc = mfma16(xf[kh], wf, acc);
      }
      #pragma unroll
      for (int r = 0; r < 4; r++)
        vals[g][r] = (m == 1) ? acc[r] * QSCALE : acc[r];
    }
    #pragma unroll
    for (int g = 0; g < 4; g++)
      #pragma unroll
      for (int r = 0; r < 4; r++)
        ylds[w * 16 + quad * 4 + r][g * 16 + l15] = f2bf(vals[g][r]);
    __syncthreads();
    if (m < 2) {
      #pragma unroll
      for (int kk = 0; kk < 2; kk++) {
        bf16x8_t f = ld16(&ylds[w * 16 + l15][kk * 32 + quad * 8]);
        *(int4*)(dsts[m] + (w * 2 + kk) * 512 + lane * 8) = __builtin_bit_cast(int4, f);
      }
    } else {
      #pragma unroll
      for (int kk = 0; kk < 2; kk++) {
        u16 tmp[8];
        #pragma unroll
        for (int j = 0; j < 8; j++)
          tmp[j] = ylds[kk * 32 + quad * 8 + j][w * 16 + l15];
        *(int4*)(dsts[2] + (kk * 4 + w) * 512 + lane * 8) = *(const int4*)tmp;
      }
    }
    __syncthreads();
  }
}

// ---------------- flash v8 (R15/R17, verified best): q-tile-32 blocks, 2 blocks/CU ----------------
__global__ __launch_bounds__(512, 4) void HeadV1_flash(
    const u16* __restrict__ qS, const u16* __restrict__ kS,
    const u16* __restrict__ vS, float* __restrict__ outg)
{
  __shared__ __align__(16) char smem[26624];
  u16  (*pT)[32][36]   = (u16 (*)[32][36])smem;
  float (*chk)[16][33] = (float (*)[16][33])smem;
  float (*stg)[68]     = (float (*)[68])(smem + 16896);
  float (*lst)[32]     = (float (*)[32])(smem + 25600);

  const int t    = threadIdx.x;
  const int w    = t >> 6;        // 0..7
  const int lane = t & 63;
  const int l15  = lane & 15;
  const int quad = lane >> 4;

  const int b = blockIdx.x & 3;
  const int u = blockIdx.x >> 2;            // 0..127
  const int j = (u < 64) ? u : (191 - u);   // q-tile-32 index, pair-balanced
  const int qt64 = j >> 1;
  const int ql0  = (j & 1) * 32;
  const int qr0  = j * 32;
  const long base = (long)b * Tt * Dd;

  union { u32 u4[4]; bf16x8_t v; } uo;
  uo.u4[0] = uo.u4[1] = uo.u4[2] = uo.u4[3] = 0x3F803F80u; // bf16 1.0 x8
  const bf16x8_t ones = uo.v;
  const f32x4_t zero4 = {0.f, 0.f, 0.f, 0.f};

  const u16* qtile = qS + ((long)(b * 64 + qt64)) * 4096 + lane * 8;
  bf16x8_t qfrag[2][2];
  #pragma unroll
  for (int ct = 0; ct < 2; ct++)
    #pragma unroll
    for (int kd = 0; kd < 2; kd++)
      qfrag[ct][kd] = ld16(qtile + ((ql0 / 16 + ct) * 2 + kd) * 512);

  f32x4_t O[4][2];   // [dt][ct]
  #pragma unroll
  for (int a = 0; a < 4; a++)
    #pragma unroll
    for (int c = 0; c < 2; c++)
      O[a][c] = zero4;
  f32x4_t Lc[2] = {zero4, zero4};

  const int nk = (j >> 1) + 1;   // kv tiles of 64

  for (int kt = w; kt < nk; kt += 8) {
    const bool ismask = (kt == nk - 1);
    const int kv0 = kt * 64;
    const u16* ktile = kS + ((long)(b * 64 + kt)) * 4096 + lane * 8;
    const u16* vtile = vS + ((long)(b * 64 + kt)) * 4096 + lane * 8;

    #pragma unroll
    for (int kk = 0; kk < 2; kk++) {     // kv-half phase
      bf16x8_t vf[4];
      #pragma unroll
      for (int dt = 0; dt < 4; dt++)
        vf[dt] = ld16(vtile + (kk * 4 + dt) * 512);

      #pragma unroll
      for (int rtl = 0; rtl < 2; rtl++) {
        const int rt = kk * 2 + rtl;
        bf16x8_t kf0 = ld16(ktile + (rt * 2 + 0) * 512);
        bf16x8_t kf1 = ld16(ktile + (rt * 2 + 1) * 512);
        #pragma unroll
        for (int ct = 0; ct < 2; ct++) {
          f32x4_t acc = zero4;
          acc = mfma16(kf0, qfrag[ct][0], acc);
          acc = mfma16(kf1, qfrag[ct][1], acc);
          if (ismask) {
            const int kvl = kv0 + rt * 16 + quad * 4;
            const int qi  = qr0 + ct * 16 + l15;
            #pragma unroll
            for (int r = 0; r < 4; r++)
              if (kvl + r > qi) acc[r] = -1e30f;   // v_exp -> 0
          }
          const float p0 = __builtin_amdgcn_exp2f(acc[0]);
          const float p1 = __builtin_amdgcn_exp2f(acc[1]);
          const float p2 = __builtin_amdgcn_exp2f(acc[2]);
          const float p3 = __builtin_amdgcn_exp2f(acc[3]);
          uint2 pk;
          pk.x = pkt(p0, p1);
          pk.y = pkt(p2, p3);
          *(uint2*)&pT[w][ct * 16 + l15][rtl * 16 + quad * 4] = pk;
        }
      }
      #pragma unroll
      for (int ct = 0; ct < 2; ct++) {
        bf16x8_t pf = ld16(&pT[w][ct * 16 + l15][quad * 8]);
        #pragma unroll
        for (int dt = 0; dt < 4; dt++)
          O[dt][ct] = mfma16(vf[dt], pf, O[dt][ct]);
        Lc[ct] = mfma16(ones, pf, Lc[ct]);
      }
    }
  }

  // ---- 8-wave merge ----
  if (quad == 0) {
    #pragma unroll
    for (int ct = 0; ct < 2; ct++)
      lst[w][ct * 16 + l15] = Lc[ct][0];
  }
  __syncthreads();  // pT dead past here; chk/stg overlay it

  #pragma unroll
  for (int dt = 0; dt < 4; dt++) {
    #pragma unroll
    for (int ct = 0; ct < 2; ct++)
      #pragma unroll
      for (int r = 0; r < 4; r++)
        chk[w][quad * 4 + r][ct * 16 + l15] = O[dt][ct][r];
    __syncthreads();
    {
      const int d2 = t >> 5, q = t & 31;   // 512 threads = 16 d x 32 q
      float s = 0.f;
      #pragma unroll
      for (int w2 = 0; w2 < 8; w2++) s += chk[w2][d2][q];
      stg[q][dt * 16 + d2] = s;
    }
    __syncthreads();
  }

  { // normalize + coalesced fp32 write: 32 q x 64 d (512 thr x 16 B)
    const int q = t >> 4, dg = t & 15;
    float L = 0.f;
    #pragma unroll
    for (int w2 = 0; w2 < 8; w2++) L += lst[w2][q];
    const float invL = 1.0f / L;
    float4 v = *(const float4*)&stg[q][dg * 4];
    v.x *= invL; v.y *= invL; v.z *= invL; v.w *= invL;
    *(float4*)(outg + base + (long)(qr0 + q) * 64 + dg * 4) = v;
  }
}

extern "C" void kernel_launch(void* const* d_in, const int* in_sizes, int n_in,
                              void* d_out, int out_size, void* d_ws, size_t ws_size,
                              hipStream_t stream) {
  (void)in_sizes; (void)n_in; (void)out_size; (void)ws_size;
  const float* x  = (const float*)d_in[0];
  const float* Wk = (const float*)d_in[1];
  const float* Wq = (const float*)d_in[2];
  const float* Wv = (const float*)d_in[3];
  float* out = (float*)d_out;
  // workspace: qS 2MB | kS 2MB | vS 2MB (all in MFMA-fragment order)
  u16* qw  = (u16*)d_ws;
  u16* kw  = qw + (size_t)Bb * Tt * Dd;
  u16* vw  = kw + (size_t)Bb * Tt * Dd;

  HeadV1_proj<<<(Bb * Tt) / 64, 256, 0, stream>>>(x, Wk, Wq, Wv, qw, kw, vw);
  HeadV1_flash<<<512, 512, 0, stream>>>(qw, kw, vw, out);
}